// Round 1
// baseline (319.303 us; speedup 1.0000x reference)
//
#include <hip/hip_runtime.h>
#include <hip/hip_bf16.h>

#define B_      8
#define N_      2000
#define H_      128
#define HEADS_  4
#define INF_    160
#define DH_     32
#define BN_     8
#define HOR_    24
#define ALPHA_  0.2f
#define EPS_    1e-5f

__device__ __forceinline__ float wredsum(float v) {
#pragma unroll
    for (int m = 1; m <= 32; m <<= 1) v += __shfl_xor(v, m, 64);
    return v;
}

// ---------------- Kernel A: Wh[b][h][n][o] = concat(x, loc_emb) @ W_gat ----------------
// 16 rows (b,n) per block, 256 threads. 1000 blocks.
__global__ __launch_bounds__(256) void k_wh(const float* __restrict__ x,
                                            const float* __restrict__ loc_emb,
                                            const float* __restrict__ W_gat,
                                            float* __restrict__ Wh) {
    __shared__ float xl[16][INF_];
    int t = threadIdx.x;
    int g0 = blockIdx.x * 16;               // global row = b*N + n  (16 | 2000, no b crossing)
    for (int idx = t; idx < 16 * INF_; idx += 256) {
        int r = idx / INF_, i = idx % INF_;
        int g = g0 + r;
        int n = g % N_;
        xl[r][i] = (i < H_) ? x[g * H_ + i] : loc_emb[n * 32 + (i - H_)];
    }
    __syncthreads();
    int col = t & 127;                      // h*32 + o
    int rset = t >> 7;                      // 0/1 -> rows 0..7 / 8..15
    int h = col >> 5, o = col & 31;
    float acc[8];
#pragma unroll
    for (int r = 0; r < 8; r++) acc[r] = 0.f;
    const float* wg = W_gat + h * (INF_ * 32) + o;
    for (int i = 0; i < INF_; i++) {
        float wv = wg[i * 32];
#pragma unroll
        for (int r = 0; r < 8; r++) acc[r] = fmaf(xl[rset * 8 + r][i], wv, acc[r]);
    }
#pragma unroll
    for (int r = 0; r < 8; r++) {
        int g = g0 + rset * 8 + r;
        int b = g / N_, n = g % N_;
        Wh[(((b * HEADS_) + h) * N_ + n) * 32 + o] = acc[r];
    }
}

// ---------------- Kernel A2: s_src / s_dst ----------------
__global__ __launch_bounds__(256) void k_ssd(const float* __restrict__ Wh,
                                             const float* __restrict__ a_src,
                                             const float* __restrict__ a_dst,
                                             float* __restrict__ s_src,
                                             float* __restrict__ s_dst) {
    int idx = blockIdx.x * 256 + threadIdx.x;   // bh*N + n
    if (idx >= B_ * HEADS_ * N_) return;
    int bh = idx / N_;
    int hh = bh & (HEADS_ - 1);
    const float4* wr = (const float4*)(Wh + (size_t)idx * 32);
    const float4* as = (const float4*)(a_src + hh * 32);
    const float4* ad = (const float4*)(a_dst + hh * 32);
    float ss = 0.f, sd = 0.f;
#pragma unroll
    for (int q = 0; q < 8; q++) {
        float4 wv = wr[q], av = as[q], dv = ad[q];
        ss += wv.x * av.x + wv.y * av.y + wv.z * av.z + wv.w * av.w;
        sd += wv.x * dv.x + wv.y * dv.y + wv.z * dv.z + wv.w * dv.w;
    }
    s_src[idx] = ss;
    s_dst[idx] = sd;
}

// ---------------- Kernel P: pack adjacency to bitmasks ----------------
// adjp[n][w], 64 words per row; bits for m>=2000 are zero.
__global__ __launch_bounds__(256) void k_pack(const int* __restrict__ adj,
                                              unsigned int* __restrict__ adjp) {
    int idx = blockIdx.x * 256 + threadIdx.x;
    if (idx >= N_ * 64) return;
    int n = idx >> 6, w = idx & 63;
    unsigned int word = 0u;
    int base = w * 32;
    if (base < N_) {
        const int* row = adj + (size_t)n * N_ + base;
        int cnt = min(32, N_ - base);
        for (int k = 0; k < cnt; k++)
            if (row[k] != 0) word |= (1u << k);
    }
    adjp[idx] = word;
}

// ---------------- Kernel B: masked softmax attention, fused PV ----------------
// grid (32 bh, 63 row-tiles), 256 threads = 4 waves, 8 rows/wave.
// No max subtraction needed: active scores are O(10); masked -> p = 0 exactly.
__global__ __launch_bounds__(256) void k_attn(const float* __restrict__ Wh,
                                              const float* __restrict__ s_src,
                                              const float* __restrict__ s_dst,
                                              const unsigned int* __restrict__ adjp,
                                              float* __restrict__ h_prime) {
    __shared__ float sdl[2048];
    __shared__ unsigned int adjl[32][64];
    __shared__ float whl[64][32];
    __shared__ float pl[4][8][64];

    int t = threadIdx.x;
    int bh = blockIdx.x;                    // 0..31
    int tile = blockIdx.y;                  // 0..62
    int w = t >> 6, lane = t & 63;
    int mi = lane >> 3, oq = lane & 7;

    const float* sdrow = s_dst + bh * N_;
    for (int i = t; i < 2048; i += 256) sdl[i] = (i < N_) ? sdrow[i] : 0.f;
    for (int i = t; i < 32 * 64; i += 256) {
        int rr = i >> 6, ww = i & 63;
        int n = tile * 32 + rr;
        adjl[rr][ww] = (n < N_) ? adjp[n * 64 + ww] : 0u;
    }
    float ssr[8];
#pragma unroll
    for (int r = 0; r < 8; r++) {
        int n = tile * 32 + w * 8 + r;
        ssr[r] = s_src[bh * N_ + min(n, N_ - 1)];
    }
    float4 acc[8];
    float lsum[8];
#pragma unroll
    for (int r = 0; r < 8; r++) { acc[r] = make_float4(0.f, 0.f, 0.f, 0.f); lsum[r] = 0.f; }

    const float4* whsrc = (const float4*)(Wh + (size_t)bh * (N_ * 32));
    float4* whl4 = (float4*)&whl[0][0];
    const int lim = N_ * 8;                 // float4 count per bh

    __syncthreads();

    for (int c = 0; c < 32; c++) {
        int m0 = c * 64;
        __syncthreads();
        {
            int q0 = m0 * 8;
            whl4[t]       = whsrc[min(q0 + t, lim - 1)];
            whl4[t + 256] = whsrc[min(q0 + t + 256, lim - 1)];
        }
        __syncthreads();

        float sd = sdl[m0 + lane];
#pragma unroll
        for (int r = 0; r < 8; r++) {
            unsigned int aw = adjl[w * 8 + r][(c << 1) | (lane >> 5)];
            unsigned int bit = (aw >> (lane & 31)) & 1u;
            float s = ssr[r] + sd;
            float ls = fmaxf(s, ALPHA_ * s);
            float pv = bit ? __expf(ls) : 0.f;
            lsum[r] += pv;
            pl[w][r][lane] = pv;
        }

        float4 whf[8];
#pragma unroll
        for (int k = 0; k < 8; k++)
            whf[k] = *(const float4*)&whl[mi * 8 + k][oq * 4];
#pragma unroll
        for (int r = 0; r < 8; r++) {
            const float* pp = &pl[w][r][mi * 8];
            float4 pa = *(const float4*)(pp);
            float4 pb = *(const float4*)(pp + 4);
            float pk[8] = {pa.x, pa.y, pa.z, pa.w, pb.x, pb.y, pb.z, pb.w};
            float4 a = acc[r];
#pragma unroll
            for (int k = 0; k < 8; k++) {
                a.x = fmaf(pk[k], whf[k].x, a.x);
                a.y = fmaf(pk[k], whf[k].y, a.y);
                a.z = fmaf(pk[k], whf[k].z, a.z);
                a.w = fmaf(pk[k], whf[k].w, a.w);
            }
            acc[r] = a;
        }
    }

    // reduce partial acc over the 8 mi-groups (lane bits 3..5); lsum over all lanes
#pragma unroll
    for (int r = 0; r < 8; r++) {
#pragma unroll
        for (int m = 8; m <= 32; m <<= 1) {
            acc[r].x += __shfl_xor(acc[r].x, m, 64);
            acc[r].y += __shfl_xor(acc[r].y, m, 64);
            acc[r].z += __shfl_xor(acc[r].z, m, 64);
            acc[r].w += __shfl_xor(acc[r].w, m, 64);
        }
        lsum[r] = wredsum(lsum[r]);
    }
    int b = bh >> 2, hh = bh & 3;
    if (lane < 8) {
#pragma unroll
        for (int r = 0; r < 8; r++) {
            int n = tile * 32 + w * 8 + r;
            if (n < N_) {
                float inv = 1.0f / lsum[r];
                float4 v = make_float4(acc[r].x * inv, acc[r].y * inv,
                                       acc[r].z * inv, acc[r].w * inv);
                *(float4*)&h_prime[((size_t)(b * N_ + n)) * H_ + hh * 32 + lane * 4] = v;
            }
        }
    }
}

// ---------------- Kernel C: LN + residual + LN + MLP head ----------------
// wave per (b,n) row; 4 rows per block; 4000 blocks.
__global__ __launch_bounds__(256) void k_head(const float* __restrict__ h_prime,
        const float* __restrict__ x, const float* __restrict__ last_step,
        const float* __restrict__ ln_gat_g, const float* __restrict__ ln_gat_b,
        const float* __restrict__ ln_g, const float* __restrict__ ln_b,
        const float* __restrict__ w_low, const float* __restrict__ b_low,
        const float* __restrict__ ln_bn_g, const float* __restrict__ ln_bn_b,
        const float* __restrict__ w_high, const float* __restrict__ b_high,
        const float* __restrict__ w_g1, const float* __restrict__ b_g1,
        const float* __restrict__ w_g2, const float* __restrict__ b_g2,
        float* __restrict__ out) {
    int t = threadIdx.x;
    int w = t >> 6, lane = t & 63;
    int g = blockIdx.x * 4 + w;             // row = b*N + n

    float2 hp = *(const float2*)&h_prime[(size_t)g * H_ + lane * 2];
    float2 xr = *(const float2*)&x[(size_t)g * H_ + lane * 2];

    // LN over h_prime
    float mean = wredsum(hp.x + hp.y) * (1.f / H_);
    float d0 = hp.x - mean, d1 = hp.y - mean;
    float var = wredsum(d0 * d0 + d1 * d1) * (1.f / H_);
    float rs = rsqrtf(var + EPS_);
    float2 gg = *(const float2*)&ln_gat_g[lane * 2];
    float2 gb = *(const float2*)&ln_gat_b[lane * 2];
    float a0 = d0 * rs * gg.x + gb.x + xr.x;
    float a1 = d1 * rs * gg.y + gb.y + xr.y;

    // LN over (gat_out + residual)
    float mean2 = wredsum(a0 + a1) * (1.f / H_);
    float e0 = a0 - mean2, e1 = a1 - mean2;
    float var2 = wredsum(e0 * e0 + e1 * e1) * (1.f / H_);
    float rs2 = rsqrtf(var2 + EPS_);
    float2 g2 = *(const float2*)&ln_g[lane * 2];
    float2 b2 = *(const float2*)&ln_b[lane * 2];
    float h0 = e0 * rs2 * g2.x + b2.x;
    float h1 = e1 * rs2 * g2.y + b2.y;

    // h @ w_low and h @ w_g1 (128x8 each); lane holds elems 2*lane, 2*lane+1
    float xlow[8], glow[8];
#pragma unroll
    for (int j = 0; j < 8; j++) {
        xlow[j] = h0 * w_low[(2 * lane) * BN_ + j] + h1 * w_low[(2 * lane + 1) * BN_ + j];
        glow[j] = h0 * w_g1[(2 * lane) * BN_ + j] + h1 * w_g1[(2 * lane + 1) * BN_ + j];
    }
#pragma unroll
    for (int j = 0; j < 8; j++) { xlow[j] = wredsum(xlow[j]); glow[j] = wredsum(glow[j]); }

    // bottleneck LN + silu (replicated across lanes)
    float mb = 0.f;
#pragma unroll
    for (int j = 0; j < 8; j++) { xlow[j] += b_low[j]; mb += xlow[j]; }
    mb *= (1.f / BN_);
    float vb = 0.f;
#pragma unroll
    for (int j = 0; j < 8; j++) { float d = xlow[j] - mb; vb += d * d; }
    vb *= (1.f / BN_);
    float rb = rsqrtf(vb + EPS_);
    float xm[8], sg[8];
#pragma unroll
    for (int j = 0; j < 8; j++) {
        float v = (xlow[j] - mb) * rb * ln_bn_g[j] + ln_bn_b[j];
        xm[j] = v / (1.f + __expf(-v));          // silu
        float u = glow[j] + b_g1[j];
        sg[j] = u / (1.f + __expf(-u));          // silu (gate path, no LN)
    }

    if (lane < HOR_) {
        float ip = b_high[lane], gt = b_g2[lane];
#pragma unroll
        for (int j = 0; j < 8; j++) {
            ip = fmaf(xm[j], w_high[j * HOR_ + lane], ip);
            gt = fmaf(sg[j], w_g2[j * HOR_ + lane], gt);
        }
        float gate = 1.f / (1.f + __expf(-gt));
        float prog = last_step[g] * __expf(-0.1f * (float)(lane + 1));
        out[(size_t)g * HOR_ + lane] = gate * ip + (1.f - gate) * prog;
    }
}

extern "C" void kernel_launch(void* const* d_in, const int* in_sizes, int n_in,
                              void* d_out, int out_size, void* d_ws, size_t ws_size,
                              hipStream_t stream) {
    const float* x        = (const float*)d_in[0];
    const int*   adj      = (const int*)d_in[1];
    const float* last_step= (const float*)d_in[2];
    const float* loc_emb  = (const float*)d_in[3];
    const float* W_gat    = (const float*)d_in[4];
    const float* a_src    = (const float*)d_in[5];
    const float* a_dst    = (const float*)d_in[6];
    const float* ln_gat_g = (const float*)d_in[7];
    const float* ln_gat_b = (const float*)d_in[8];
    const float* ln_g     = (const float*)d_in[9];
    const float* ln_b     = (const float*)d_in[10];
    const float* w_low    = (const float*)d_in[11];
    const float* b_low    = (const float*)d_in[12];
    const float* ln_bn_g  = (const float*)d_in[13];
    const float* ln_bn_b  = (const float*)d_in[14];
    const float* w_high   = (const float*)d_in[15];
    const float* b_high   = (const float*)d_in[16];
    const float* w_g1     = (const float*)d_in[17];
    const float* b_g1     = (const float*)d_in[18];
    const float* w_g2     = (const float*)d_in[19];
    const float* b_g2     = (const float*)d_in[20];
    float* out = (float*)d_out;

    float* ws = (float*)d_ws;
    float* Wh      = ws;                      // B*HEADS*N*32 = 2,048,000 floats
    float* s_src   = ws + 2048000;            // 64,000
    float* s_dst   = ws + 2112000;            // 64,000
    float* h_prime = ws + 2176000;            // 2,048,000
    unsigned int* adjp = (unsigned int*)(ws + 4224000); // N*64 = 128,000 words

    hipLaunchKernelGGL(k_wh,   dim3(1000), dim3(256), 0, stream, x, loc_emb, W_gat, Wh);
    hipLaunchKernelGGL(k_ssd,  dim3(250),  dim3(256), 0, stream, Wh, a_src, a_dst, s_src, s_dst);
    hipLaunchKernelGGL(k_pack, dim3(500),  dim3(256), 0, stream, adj, adjp);
    hipLaunchKernelGGL(k_attn, dim3(32, 63), dim3(256), 0, stream, Wh, s_src, s_dst, adjp, h_prime);
    hipLaunchKernelGGL(k_head, dim3(4000), dim3(256), 0, stream, h_prime, x, last_step,
                       ln_gat_g, ln_gat_b, ln_g, ln_b, w_low, b_low, ln_bn_g, ln_bn_b,
                       w_high, b_high, w_g1, b_g1, w_g2, b_g2, out);
}

// Round 2
// 202.610 us; speedup vs baseline: 1.5760x; 1.5760x over previous
//
#include <hip/hip_runtime.h>
#include <hip/hip_bf16.h>

#define B_      8
#define N_      2000
#define H_      128
#define HEADS_  4
#define INF_    160
#define DH_     32
#define BN_     8
#define HOR_    24
#define ALPHA_  0.2f
#define EPS_    1e-5f
#define LOG2E_  1.4426950408889634f

typedef __bf16 bf16x4 __attribute__((ext_vector_type(4)));
typedef __bf16 bf16x8 __attribute__((ext_vector_type(8)));
typedef float  f32x16 __attribute__((ext_vector_type(16)));

__device__ __forceinline__ float wredsum(float v) {
#pragma unroll
    for (int m = 1; m <= 32; m <<= 1) v += __shfl_xor(v, m, 64);
    return v;
}

// ---------------- Kernel WPREP: pack W_gat into MFMA B-fragment layout, bf16 hi/lo ----
// Wpk[idx] layout: [(h*10+s)*64 + lane]*8 + j ; hi at 0, lo at +20480.
__global__ __launch_bounds__(256) void k_wprep(const float* __restrict__ W_gat,
                                               __bf16* __restrict__ Wpk) {
    int idx = blockIdx.x * 256 + threadIdx.x;
    if (idx >= 4 * 10 * 512) return;
    int h = idx / 5120, rem = idx % 5120;
    int s = rem / 512, q = rem % 512;
    int l = q >> 3, j = q & 7;
    int k = s * 16 + (l >> 5) * 8 + j;
    int o = l & 31;
    float v = W_gat[(h * INF_ + k) * 32 + o];
    __bf16 hi = (__bf16)v;
    Wpk[idx] = hi;
    Wpk[idx + 20480] = (__bf16)(v - (float)hi);
}

// ---------------- Kernel WH: Wh = concat(x, loc_emb) @ W_gat via split-bf16 MFMA -------
// 500 blocks x 256 thr; block = 32 rows, wave w = head w. 30 MFMAs/wave.
__global__ __launch_bounds__(256) void k_wh(const float* __restrict__ x,
                                            const float* __restrict__ loc_emb,
                                            const __bf16* __restrict__ Wpk,
                                            float* __restrict__ Wh,
                                            __bf16* __restrict__ Whbf) {
    __shared__ __bf16 xhi[32][164];          // pad 164: 2-way (free) bank access on b64
    __shared__ __bf16 xlo[32][164];
    int t = threadIdx.x;
    int g0 = blockIdx.x * 32;
#pragma unroll
    for (int it = 0; it < 5; it++) {         // 1280 float4 = 32 rows x 40
        int idx = it * 256 + t;
        int r = idx / 40, c4 = idx % 40;
        int i4 = c4 * 4;
        float4 v;
        if (i4 < H_) {
            v = *(const float4*)&x[(size_t)(g0 + r) * H_ + i4];
        } else {
            int n = (g0 + r) % N_;
            v = *(const float4*)&loc_emb[n * 32 + (i4 - H_)];
        }
        bf16x4 h4, l4;
        h4[0] = (__bf16)v.x; l4[0] = (__bf16)(v.x - (float)h4[0]);
        h4[1] = (__bf16)v.y; l4[1] = (__bf16)(v.y - (float)h4[1]);
        h4[2] = (__bf16)v.z; l4[2] = (__bf16)(v.z - (float)h4[2]);
        h4[3] = (__bf16)v.w; l4[3] = (__bf16)(v.w - (float)h4[3]);
        *(bf16x4*)&xhi[r][i4] = h4;
        *(bf16x4*)&xlo[r][i4] = l4;
    }
    __syncthreads();

    int lane = t & 63, w = t >> 6;           // w = head
    int ln = lane & 31, grp = lane >> 5;
    f32x16 acc;
#pragma unroll
    for (int r = 0; r < 16; r++) acc[r] = 0.0f;

    for (int s = 0; s < 10; s++) {
        int off = s * 16 + grp * 8;
        bf16x4 a0 = *(const bf16x4*)&xhi[ln][off];
        bf16x4 a1 = *(const bf16x4*)&xhi[ln][off + 4];
        bf16x4 c0 = *(const bf16x4*)&xlo[ln][off];
        bf16x4 c1 = *(const bf16x4*)&xlo[ln][off + 4];
        bf16x8 ahi, alo;
#pragma unroll
        for (int q = 0; q < 4; q++) {
            ahi[q] = a0[q]; ahi[q + 4] = a1[q];
            alo[q] = c0[q]; alo[q + 4] = c1[q];
        }
        const __bf16* wp = Wpk + ((w * 10 + s) * 64 + lane) * 8;
        bf16x8 bhi = *(const bf16x8*)wp;
        bf16x8 blo = *(const bf16x8*)(wp + 20480);
        acc = __builtin_amdgcn_mfma_f32_32x32x16_bf16(ahi, bhi, acc, 0, 0, 0);
        acc = __builtin_amdgcn_mfma_f32_32x32x16_bf16(ahi, blo, acc, 0, 0, 0);
        acc = __builtin_amdgcn_mfma_f32_32x32x16_bf16(alo, bhi, acc, 0, 0, 0);
    }
#pragma unroll
    for (int r = 0; r < 16; r++) {
        int nr = (r & 3) + 8 * (r >> 2) + 4 * grp;
        int g = g0 + nr;
        int b = g / N_, n = g - b * N_;
        size_t o = ((size_t)((b * HEADS_ + w) * N_ + n)) * 32 + ln;
        float val = acc[r];
        Wh[o] = val;
        Whbf[o] = (__bf16)val;
    }
}

// ---------------- Kernel A2: s_src / s_dst (from f32 Wh) ----------------
__global__ __launch_bounds__(256) void k_ssd(const float* __restrict__ Wh,
                                             const float* __restrict__ a_src,
                                             const float* __restrict__ a_dst,
                                             float* __restrict__ s_src,
                                             float* __restrict__ s_dst) {
    int idx = blockIdx.x * 256 + threadIdx.x;   // bh*N + n
    if (idx >= B_ * HEADS_ * N_) return;
    int bh = idx / N_;
    int hh = bh & (HEADS_ - 1);
    const float4* wr = (const float4*)(Wh + (size_t)idx * 32);
    const float4* as = (const float4*)(a_src + hh * 32);
    const float4* ad = (const float4*)(a_dst + hh * 32);
    float ss = 0.f, sd = 0.f;
#pragma unroll
    for (int q = 0; q < 8; q++) {
        float4 wv = wr[q], av = as[q], dv = ad[q];
        ss += wv.x * av.x + wv.y * av.y + wv.z * av.z + wv.w * av.w;
        sd += wv.x * dv.x + wv.y * dv.y + wv.z * dv.z + wv.w * dv.w;
    }
    s_src[idx] = ss;
    s_dst[idx] = sd;
}

// ---------------- Kernel P: pack adjacency to bitmasks via ballot ----------------
__global__ __launch_bounds__(256) void k_pack(const int* __restrict__ adj,
                                              unsigned int* __restrict__ adjp) {
    int t = threadIdx.x;
    int lane = t & 63, w = t >> 6;
    int n = blockIdx.x * 4 + w;                 // 500 blocks x 4 waves = 2000 rows
    const int* row = adj + (size_t)n * N_;
#pragma unroll 4
    for (int it = 0; it < 32; it++) {
        int base = it * 64 + lane;
        int pred = (base < N_) ? (row[base] != 0) : 0;
        unsigned long long mask = __ballot(pred);
        if (lane == 0) {
            adjp[n * 64 + it * 2]     = (unsigned int)mask;
            adjp[n * 64 + it * 2 + 1] = (unsigned int)(mask >> 32);
        }
    }
}

// ---------------- Kernel B: flash-style masked attention via MFMA ----------------
// grid (16 tiles, 32 bh) x 256 thr. Wave = 32 n-rows; block = 128 rows.
// Lane l: n-row = l&31, m-slice k = 8*(l>>5)+j  (A-fragment layout of 32x32x16 mfma).
__global__ __launch_bounds__(256) void k_attn(const __bf16* __restrict__ Whbf,
                                              const float* __restrict__ s_src,
                                              const float* __restrict__ s_dst,
                                              const unsigned int* __restrict__ adjp,
                                              float* __restrict__ h_prime) {
    __shared__ float sdl[2048];
    __shared__ unsigned int adjl[128][66];   // pad 66 -> 2-way (free)
    __shared__ __bf16 whT[32][68];           // [o][m], pad 68 -> 2-way on b64
    __shared__ float lsumS[4][32];

    int t = threadIdx.x;
    int tile = blockIdx.x;                   // 0..15
    int bh = blockIdx.y;                     // 0..31
    int w = t >> 6, lane = t & 63;
    int ln = lane & 31, grp = lane >> 5;

    const float* sdrow = s_dst + bh * N_;
    for (int i = t; i < 2048; i += 256) sdl[i] = (i < N_) ? sdrow[i] * LOG2E_ : 0.f;
    for (int i = t; i < 128 * 64; i += 256) {
        int rr = i >> 6, ww = i & 63;
        int n = tile * 128 + rr;
        adjl[rr][ww] = (n < N_) ? adjp[n * 64 + ww] : 0u;
    }
    int myn = tile * 128 + w * 32 + ln;
    float ssr = s_src[bh * N_ + min(myn, N_ - 1)] * LOG2E_;

    f32x16 acc;
#pragma unroll
    for (int r = 0; r < 16; r++) acc[r] = 0.0f;
    float lsum = 0.f;

    for (int c = 0; c < 32; c++) {
        __syncthreads();
        {   // stage Wh chunk [64 m][32 o] -> whT[o][m] bf16 (transposed)
            int ml = t >> 2, o0 = (t & 3) * 8;
            int mm = min(c * 64 + ml, N_ - 1);
            bf16x8 v = *(const bf16x8*)&Whbf[((size_t)bh * N_ + mm) * 32 + o0];
#pragma unroll
            for (int q = 0; q < 8; q++) whT[o0 + q][ml] = v[q];
        }
        __syncthreads();
#pragma unroll
        for (int s = 0; s < 4; s++) {
            int moff = s * 16 + grp * 8;
            float4 sd0 = *(const float4*)&sdl[c * 64 + moff];
            float4 sd1 = *(const float4*)&sdl[c * 64 + moff + 4];
            unsigned int word = adjl[w * 32 + ln][c * 2 + (s >> 1)];
            unsigned int mbyte = (word >> ((s & 1) * 16 + grp * 8)) & 0xffu;
            float sdv[8] = {sd0.x, sd0.y, sd0.z, sd0.w, sd1.x, sd1.y, sd1.z, sd1.w};
            bf16x8 a;
#pragma unroll
            for (int jj = 0; jj < 8; jj++) {
                float sc = ssr + sdv[jj];
                float ls = fmaxf(sc, 0.2f * sc);     // leakyrelu in log2 domain
                float e = __builtin_amdgcn_exp2f(ls);
                float pv = (mbyte & (1u << jj)) ? e : 0.0f;
                lsum += pv;
                a[jj] = (__bf16)pv;
            }
            bf16x4 b0 = *(const bf16x4*)&whT[ln][moff];
            bf16x4 b1 = *(const bf16x4*)&whT[ln][moff + 4];
            bf16x8 b;
#pragma unroll
            for (int q = 0; q < 4; q++) { b[q] = b0[q]; b[q + 4] = b1[q]; }
            acc = __builtin_amdgcn_mfma_f32_32x32x16_bf16(a, b, acc, 0, 0, 0);
        }
    }

    lsum += __shfl_xor(lsum, 32, 64);
    if (lane < 32) lsumS[w][ln] = lsum;
    __syncthreads();

    int b = bh >> 2, hh = bh & 3;
#pragma unroll
    for (int r = 0; r < 16; r++) {
        int nr = (r & 3) + 8 * (r >> 2) + 4 * grp;
        int n = tile * 128 + w * 32 + nr;
        if (n < N_) {
            float inv = 1.0f / lsumS[w][nr];
            h_prime[((size_t)(b * N_ + n)) * H_ + hh * 32 + ln] = acc[r] * inv;
        }
    }
}

// ---------------- Kernel C: LN + residual + LN + MLP head ----------------
__global__ __launch_bounds__(256) void k_head(const float* __restrict__ h_prime,
        const float* __restrict__ x, const float* __restrict__ last_step,
        const float* __restrict__ ln_gat_g, const float* __restrict__ ln_gat_b,
        const float* __restrict__ ln_g, const float* __restrict__ ln_b,
        const float* __restrict__ w_low, const float* __restrict__ b_low,
        const float* __restrict__ ln_bn_g, const float* __restrict__ ln_bn_b,
        const float* __restrict__ w_high, const float* __restrict__ b_high,
        const float* __restrict__ w_g1, const float* __restrict__ b_g1,
        const float* __restrict__ w_g2, const float* __restrict__ b_g2,
        float* __restrict__ out) {
    __shared__ float hsh[4][128];
    __shared__ float xms[4][8], sgs[4][8];
    int t = threadIdx.x;
    int w = t >> 6, lane = t & 63;
    int g = blockIdx.x * 4 + w;             // row = b*N + n

    float2 hp = *(const float2*)&h_prime[(size_t)g * H_ + lane * 2];
    float2 xr = *(const float2*)&x[(size_t)g * H_ + lane * 2];

    float mean = wredsum(hp.x + hp.y) * (1.f / H_);
    float d0 = hp.x - mean, d1 = hp.y - mean;
    float var = wredsum(d0 * d0 + d1 * d1) * (1.f / H_);
    float rs = rsqrtf(var + EPS_);
    float2 gg = *(const float2*)&ln_gat_g[lane * 2];
    float2 gb = *(const float2*)&ln_gat_b[lane * 2];
    float a0 = d0 * rs * gg.x + gb.x + xr.x;
    float a1 = d1 * rs * gg.y + gb.y + xr.y;

    float mean2 = wredsum(a0 + a1) * (1.f / H_);
    float e0 = a0 - mean2, e1 = a1 - mean2;
    float var2 = wredsum(e0 * e0 + e1 * e1) * (1.f / H_);
    float rs2 = rsqrtf(var2 + EPS_);
    float2 g2 = *(const float2*)&ln_g[lane * 2];
    float2 b2 = *(const float2*)&ln_b[lane * 2];
    float h0 = e0 * rs2 * g2.x + b2.x;
    float h1 = e1 * rs2 * g2.y + b2.y;

    *(float2*)&hsh[w][2 * lane] = make_float2(h0, h1);
    __syncthreads();

    // lane = i16*8 + j : partial dot over 16 h-elems for column j
    int j = lane & 7, i16 = lane >> 3;
    float xa = 0.f, ga = 0.f;
#pragma unroll
    for (int q = 0; q < 16; q++) {
        int qq = (q + 2 * i16) & 15;         // bank-rotation: conflict-free
        int i = i16 * 16 + qq;
        float hv = hsh[w][i];
        xa = fmaf(hv, w_low[i * BN_ + j], xa);
        ga = fmaf(hv, w_g1[i * BN_ + j], ga);
    }
#pragma unroll
    for (int m = 8; m <= 32; m <<= 1) {
        xa += __shfl_xor(xa, m, 64);
        ga += __shfl_xor(ga, m, 64);
    }
    xa += b_low[j];

    // bottleneck LN across the 8 j's (lane bits 0..2)
    float mb = xa;
#pragma unroll
    for (int m = 1; m <= 4; m <<= 1) mb += __shfl_xor(mb, m, 64);
    mb *= (1.f / BN_);
    float db = xa - mb;
    float vb = db * db;
#pragma unroll
    for (int m = 1; m <= 4; m <<= 1) vb += __shfl_xor(vb, m, 64);
    vb *= (1.f / BN_);
    float rb = rsqrtf(vb + EPS_);
    float v = db * rb * ln_bn_g[j] + ln_bn_b[j];
    float xm = v / (1.f + __expf(-v));
    float u = ga + b_g1[j];
    float sg = u / (1.f + __expf(-u));
    if (lane < 8) { xms[w][lane] = xm; sgs[w][lane] = sg; }
    __syncthreads();

    if (lane < HOR_) {
        float ip = b_high[lane], gt = b_g2[lane];
#pragma unroll
        for (int jj = 0; jj < 8; jj++) {
            ip = fmaf(xms[w][jj], w_high[jj * HOR_ + lane], ip);
            gt = fmaf(sgs[w][jj], w_g2[jj * HOR_ + lane], gt);
        }
        float gate = 1.f / (1.f + __expf(-gt));
        float prog = last_step[g] * __expf(-0.1f * (float)(lane + 1));
        out[(size_t)g * HOR_ + lane] = gate * ip + (1.f - gate) * prog;
    }
}

extern "C" void kernel_launch(void* const* d_in, const int* in_sizes, int n_in,
                              void* d_out, int out_size, void* d_ws, size_t ws_size,
                              hipStream_t stream) {
    const float* x        = (const float*)d_in[0];
    const int*   adj      = (const int*)d_in[1];
    const float* last_step= (const float*)d_in[2];
    const float* loc_emb  = (const float*)d_in[3];
    const float* W_gat    = (const float*)d_in[4];
    const float* a_src    = (const float*)d_in[5];
    const float* a_dst    = (const float*)d_in[6];
    const float* ln_gat_g = (const float*)d_in[7];
    const float* ln_gat_b = (const float*)d_in[8];
    const float* ln_g     = (const float*)d_in[9];
    const float* ln_b     = (const float*)d_in[10];
    const float* w_low    = (const float*)d_in[11];
    const float* b_low    = (const float*)d_in[12];
    const float* ln_bn_g  = (const float*)d_in[13];
    const float* ln_bn_b  = (const float*)d_in[14];
    const float* w_high   = (const float*)d_in[15];
    const float* b_high   = (const float*)d_in[16];
    const float* w_g1     = (const float*)d_in[17];
    const float* b_g1     = (const float*)d_in[18];
    const float* w_g2     = (const float*)d_in[19];
    const float* b_g2     = (const float*)d_in[20];
    float* out = (float*)d_out;

    float* ws = (float*)d_ws;
    float*        Wh      = ws;                                  // 2,048,000 f32
    float*        h_prime = ws + 2048000;                        // 2,048,000 f32
    float*        s_src   = ws + 4096000;                        // 64,000
    float*        s_dst   = ws + 4160000;                        // 64,000
    unsigned int* adjp    = (unsigned int*)(ws + 4224000);       // 128,000 u32
    __bf16*       Whbf    = (__bf16*)(ws + 4352000);             // 2,048,000 bf16
    __bf16*       Wpk     = (__bf16*)(ws + 5376000);             // 2 x 20,480 bf16

    hipLaunchKernelGGL(k_wprep, dim3(80),      dim3(256), 0, stream, W_gat, Wpk);
    hipLaunchKernelGGL(k_pack,  dim3(500),     dim3(256), 0, stream, adj, adjp);
    hipLaunchKernelGGL(k_wh,    dim3(500),     dim3(256), 0, stream, x, loc_emb, Wpk, Wh, Whbf);
    hipLaunchKernelGGL(k_ssd,   dim3(250),     dim3(256), 0, stream, Wh, a_src, a_dst, s_src, s_dst);
    hipLaunchKernelGGL(k_attn,  dim3(16, 32),  dim3(256), 0, stream, Whbf, s_src, s_dst, adjp, h_prime);
    hipLaunchKernelGGL(k_head,  dim3(4000),    dim3(256), 0, stream, h_prime, x, last_step,
                       ln_gat_g, ln_gat_b, ln_g, ln_b, w_low, b_low, ln_bn_g, ln_bn_b,
                       w_high, b_high, w_g1, b_g1, w_g2, b_g2, out);
}

// Round 3
// 186.712 us; speedup vs baseline: 1.7101x; 1.0851x over previous
//
#include <hip/hip_runtime.h>
#include <hip/hip_bf16.h>

#define B_      8
#define N_      2000
#define H_      128
#define HEADS_  4
#define INF_    160
#define DH_     32
#define BN_     8
#define HOR_    24
#define ALPHA_  0.2f
#define EPS_    1e-5f
#define LOG2E_  1.4426950408889634f

typedef __bf16 bf16x4 __attribute__((ext_vector_type(4)));
typedef __bf16 bf16x8 __attribute__((ext_vector_type(8)));
typedef float  f32x16 __attribute__((ext_vector_type(16)));

__device__ __forceinline__ float wredsum(float v) {
#pragma unroll
    for (int m = 1; m <= 32; m <<= 1) v += __shfl_xor(v, m, 64);
    return v;
}

// ---------------- Kernel WPREP: pack W_gat into MFMA B-fragment layout, bf16 hi/lo ----
__global__ __launch_bounds__(256) void k_wprep(const float* __restrict__ W_gat,
                                               __bf16* __restrict__ Wpk) {
    int idx = blockIdx.x * 256 + threadIdx.x;
    if (idx >= 4 * 10 * 512) return;
    int h = idx / 5120, rem = idx % 5120;
    int s = rem / 512, q = rem % 512;
    int l = q >> 3, j = q & 7;
    int k = s * 16 + (l >> 5) * 8 + j;
    int o = l & 31;
    float v = W_gat[(h * INF_ + k) * 32 + o];
    __bf16 hi = (__bf16)v;
    Wpk[idx] = hi;
    Wpk[idx + 20480] = (__bf16)(v - (float)hi);
}

// ---------------- Kernel WH: Wh = concat(x, loc_emb) @ W_gat via split-bf16 MFMA -------
__global__ __launch_bounds__(256) void k_wh(const float* __restrict__ x,
                                            const float* __restrict__ loc_emb,
                                            const __bf16* __restrict__ Wpk,
                                            float* __restrict__ Wh,
                                            __bf16* __restrict__ Whbf) {
    __shared__ __bf16 xhi[32][164];
    __shared__ __bf16 xlo[32][164];
    int t = threadIdx.x;
    int g0 = blockIdx.x * 32;
#pragma unroll
    for (int it = 0; it < 5; it++) {
        int idx = it * 256 + t;
        int r = idx / 40, c4 = idx % 40;
        int i4 = c4 * 4;
        float4 v;
        if (i4 < H_) {
            v = *(const float4*)&x[(size_t)(g0 + r) * H_ + i4];
        } else {
            int n = (g0 + r) % N_;
            v = *(const float4*)&loc_emb[n * 32 + (i4 - H_)];
        }
        bf16x4 h4, l4;
        h4[0] = (__bf16)v.x; l4[0] = (__bf16)(v.x - (float)h4[0]);
        h4[1] = (__bf16)v.y; l4[1] = (__bf16)(v.y - (float)h4[1]);
        h4[2] = (__bf16)v.z; l4[2] = (__bf16)(v.z - (float)h4[2]);
        h4[3] = (__bf16)v.w; l4[3] = (__bf16)(v.w - (float)h4[3]);
        *(bf16x4*)&xhi[r][i4] = h4;
        *(bf16x4*)&xlo[r][i4] = l4;
    }
    __syncthreads();

    int lane = t & 63, w = t >> 6;           // w = head
    int ln = lane & 31, grp = lane >> 5;
    f32x16 acc;
#pragma unroll
    for (int r = 0; r < 16; r++) acc[r] = 0.0f;

    for (int s = 0; s < 10; s++) {
        int off = s * 16 + grp * 8;
        bf16x4 a0 = *(const bf16x4*)&xhi[ln][off];
        bf16x4 a1 = *(const bf16x4*)&xhi[ln][off + 4];
        bf16x4 c0 = *(const bf16x4*)&xlo[ln][off];
        bf16x4 c1 = *(const bf16x4*)&xlo[ln][off + 4];
        bf16x8 ahi, alo;
#pragma unroll
        for (int q = 0; q < 4; q++) {
            ahi[q] = a0[q]; ahi[q + 4] = a1[q];
            alo[q] = c0[q]; alo[q + 4] = c1[q];
        }
        const __bf16* wp = Wpk + ((w * 10 + s) * 64 + lane) * 8;
        bf16x8 bhi = *(const bf16x8*)wp;
        bf16x8 blo = *(const bf16x8*)(wp + 20480);
        acc = __builtin_amdgcn_mfma_f32_32x32x16_bf16(ahi, bhi, acc, 0, 0, 0);
        acc = __builtin_amdgcn_mfma_f32_32x32x16_bf16(ahi, blo, acc, 0, 0, 0);
        acc = __builtin_amdgcn_mfma_f32_32x32x16_bf16(alo, bhi, acc, 0, 0, 0);
    }
#pragma unroll
    for (int r = 0; r < 16; r++) {
        int nr = (r & 3) + 8 * (r >> 2) + 4 * grp;
        int g = g0 + nr;
        int b = g / N_, n = g - b * N_;
        size_t o = ((size_t)((b * HEADS_ + w) * N_ + n)) * 32 + ln;
        float val = acc[r];
        Wh[o] = val;
        Whbf[o] = (__bf16)val;
    }
}

// ---------------- Kernel EF: per-row/col exp factors ----------------
// e1=exp(ss), e5=exp(0.2 ss) per n (src); f1=exp(sd), f5=exp(0.2 sd) per m (dst).
__global__ __launch_bounds__(256) void k_ef(const float* __restrict__ Wh,
                                            const float* __restrict__ a_src,
                                            const float* __restrict__ a_dst,
                                            float2* __restrict__ Etab,
                                            float2* __restrict__ Ftab) {
    int idx = blockIdx.x * 256 + threadIdx.x;   // bh*N + n
    if (idx >= B_ * HEADS_ * N_) return;
    int bh = idx / N_;
    int hh = bh & (HEADS_ - 1);
    const float4* wr = (const float4*)(Wh + (size_t)idx * 32);
    const float4* as = (const float4*)(a_src + hh * 32);
    const float4* ad = (const float4*)(a_dst + hh * 32);
    float ss = 0.f, sd = 0.f;
#pragma unroll
    for (int q = 0; q < 8; q++) {
        float4 wv = wr[q], av = as[q], dv = ad[q];
        ss += wv.x * av.x + wv.y * av.y + wv.z * av.z + wv.w * av.w;
        sd += wv.x * dv.x + wv.y * dv.y + wv.z * dv.z + wv.w * dv.w;
    }
    Etab[idx] = make_float2(exp2f(ss * LOG2E_), exp2f(0.2f * ss * LOG2E_));
    Ftab[idx] = make_float2(exp2f(sd * LOG2E_), exp2f(0.2f * sd * LOG2E_));
}

// ---------------- Kernel P: pack adjacency to bitmasks via ballot ----------------
__global__ __launch_bounds__(256) void k_pack(const int* __restrict__ adj,
                                              unsigned int* __restrict__ adjp) {
    int t = threadIdx.x;
    int lane = t & 63, w = t >> 6;
    int n = blockIdx.x * 4 + w;
    const int* row = adj + (size_t)n * N_;
#pragma unroll 4
    for (int it = 0; it < 32; it++) {
        int base = it * 64 + lane;
        int pred = (base < N_) ? (row[base] != 0) : 0;
        unsigned long long mask = __ballot(pred);
        if (lane == 0) {
            adjp[n * 64 + it * 2]     = (unsigned int)mask;
            adjp[n * 64 + it * 2 + 1] = (unsigned int)(mask >> 32);
        }
    }
}

// ---------------- Kernel TR: Whbf [bh][n][o] -> WhT [bh][o][2048] (bf16) -----------
__global__ __launch_bounds__(256) void k_tr(const __bf16* __restrict__ Whbf,
                                            __bf16* __restrict__ WhT) {
    __shared__ __bf16 T[32][136];
    int t = threadIdx.x;
    int tile = blockIdx.x;                   // 0..15 (128 n each)
    int bh = blockIdx.y;
    int nl = t >> 1, oh = (t & 1) * 16;
    int n = tile * 128 + nl;
    if (n < N_) {
        bf16x8 v0 = *(const bf16x8*)&Whbf[((size_t)bh * N_ + n) * 32 + oh];
        bf16x8 v1 = *(const bf16x8*)&Whbf[((size_t)bh * N_ + n) * 32 + oh + 8];
#pragma unroll
        for (int q = 0; q < 8; q++) { T[oh + q][nl] = v0[q]; T[oh + 8 + q][nl] = v1[q]; }
    } else {
#pragma unroll
        for (int q = 0; q < 16; q++) T[oh + q][nl] = (__bf16)0.f;
    }
    __syncthreads();
    int o = t >> 3, nb = (t & 7) * 16;
    bf16x8 w0 = *(const bf16x8*)&T[o][nb];
    bf16x8 w1 = *(const bf16x8*)&T[o][nb + 8];
    size_t base = ((size_t)bh * 32 + o) * 2048 + tile * 128 + nb;
    *(bf16x8*)&WhT[base] = w0;
    *(bf16x8*)&WhT[base + 8] = w1;
}

// ---------------- Kernel B: barrier-free masked attention via MFMA ----------------
// grid (32 tiles x 32 bh) x 256 thr. Tile = 64 rows; wave pair (rg) shares 32 rows,
// splits m into c-halves. pv = max(e1n*f1m, e5n*f5m) masked -> no exp in hot loop.
__global__ __launch_bounds__(256, 4) void k_attn(const __bf16* __restrict__ WhT,
                                                 const float2* __restrict__ Etab,
                                                 const float2* __restrict__ Ftab,
                                                 const unsigned int* __restrict__ adjp,
                                                 float* __restrict__ h_prime) {
    __shared__ float2 fl[2048];              // 16 KB
    __shared__ float cmb[2][64][17];         // 8.7 KB (17: gcd(17,32)=1, conflict-free)
    __shared__ float lswA[2][32];

    int t = threadIdx.x;
    int tile = blockIdx.x;                   // 0..31
    int bh = blockIdx.y;                     // 0..31
    int w = t >> 6, lane = t & 63;
    int ln = lane & 31, grp = lane >> 5;
    int rg = w >> 1, ch = w & 1;

    const float2* Fb = Ftab + (size_t)bh * N_;
    for (int i = t; i < 2048; i += 256)
        fl[i] = (i < N_) ? Fb[i] : make_float2(0.f, 0.f);

    int row = tile * 64 + rg * 32 + ln;
    int rclamp = min(row, N_ - 1);
    float2 ee = Etab[(size_t)bh * N_ + rclamp];
    float e1 = ee.x, e5 = ee.y;

    const unsigned int* arow = adjp + (size_t)rclamp * 64;
    const __bf16* bbase = WhT + ((size_t)bh * 32 + ln) * 2048;

    f32x16 acc;
#pragma unroll
    for (int r = 0; r < 16; r++) acc[r] = 0.0f;
    float lsum = 0.f;

    __syncthreads();

    for (int ci = 0; ci < 16; ci++) {
        int c = ch * 16 + ci;
        int m0 = c * 64;
        uint2 aw = *(const uint2*)&arow[c * 2];
        bf16x8 bfr[4];
#pragma unroll
        for (int s = 0; s < 4; s++)
            bfr[s] = *(const bf16x8*)&bbase[m0 + s * 16 + grp * 8];
#pragma unroll
        for (int s = 0; s < 4; s++) {
            int mo = m0 + s * 16 + grp * 8;
            unsigned int word = (s < 2) ? aw.x : aw.y;
            unsigned int mbyte = (word >> ((s & 1) * 16 + grp * 8)) & 0xffu;
            bf16x8 a;
#pragma unroll
            for (int jj = 0; jj < 8; jj++) {
                float2 ff = fl[mo + jj];
                float pv = fmaxf(e1 * ff.x, e5 * ff.y);   // = exp(lrelu(ssr+sd))
                pv = (mbyte & (1u << jj)) ? pv : 0.0f;
                lsum += pv;
                a[jj] = (__bf16)pv;
            }
            acc = __builtin_amdgcn_mfma_f32_32x32x16_bf16(a, bfr[s], acc, 0, 0, 0);
        }
    }

    // combine grp halves (same row, different j-slots)
    lsum += __shfl_xor(lsum, 32, 64);

    if (ch == 1) {
#pragma unroll
        for (int r = 0; r < 16; r++) cmb[rg][lane][r] = acc[r];
        if (lane < 32) lswA[rg][ln] = lsum;
    }
    __syncthreads();
    if (ch == 0) {
#pragma unroll
        for (int r = 0; r < 16; r++) acc[r] += cmb[rg][lane][r];
        float invt = 1.0f / (lsum + lswA[rg][ln]);   // row ln total
        int bq = bh >> 2, hh = bh & 3;
#pragma unroll
        for (int r = 0; r < 16; r++) {
            int nr = (r & 3) + 8 * (r >> 2) + 4 * grp;
            int n = tile * 64 + rg * 32 + nr;
            float inv_r = __shfl(invt, nr, 64);
            if (n < N_) {
                h_prime[((size_t)(bq * N_ + n)) * H_ + hh * 32 + ln] = acc[r] * inv_r;
            }
        }
    }
}

// ---------------- Kernel C: LN + residual + LN + MLP head ----------------
__global__ __launch_bounds__(256) void k_head(const float* __restrict__ h_prime,
        const float* __restrict__ x, const float* __restrict__ last_step,
        const float* __restrict__ ln_gat_g, const float* __restrict__ ln_gat_b,
        const float* __restrict__ ln_g, const float* __restrict__ ln_b,
        const float* __restrict__ w_low, const float* __restrict__ b_low,
        const float* __restrict__ ln_bn_g, const float* __restrict__ ln_bn_b,
        const float* __restrict__ w_high, const float* __restrict__ b_high,
        const float* __restrict__ w_g1, const float* __restrict__ b_g1,
        const float* __restrict__ w_g2, const float* __restrict__ b_g2,
        float* __restrict__ out) {
    __shared__ float hsh[4][128];
    __shared__ float xms[4][8], sgs[4][8];
    int t = threadIdx.x;
    int w = t >> 6, lane = t & 63;
    int g = blockIdx.x * 4 + w;

    float2 hp = *(const float2*)&h_prime[(size_t)g * H_ + lane * 2];
    float2 xr = *(const float2*)&x[(size_t)g * H_ + lane * 2];

    float mean = wredsum(hp.x + hp.y) * (1.f / H_);
    float d0 = hp.x - mean, d1 = hp.y - mean;
    float var = wredsum(d0 * d0 + d1 * d1) * (1.f / H_);
    float rs = rsqrtf(var + EPS_);
    float2 gg = *(const float2*)&ln_gat_g[lane * 2];
    float2 gb = *(const float2*)&ln_gat_b[lane * 2];
    float a0 = d0 * rs * gg.x + gb.x + xr.x;
    float a1 = d1 * rs * gg.y + gb.y + xr.y;

    float mean2 = wredsum(a0 + a1) * (1.f / H_);
    float e0 = a0 - mean2, e1 = a1 - mean2;
    float var2 = wredsum(e0 * e0 + e1 * e1) * (1.f / H_);
    float rs2 = rsqrtf(var2 + EPS_);
    float2 g2 = *(const float2*)&ln_g[lane * 2];
    float2 b2 = *(const float2*)&ln_b[lane * 2];
    float h0 = e0 * rs2 * g2.x + b2.x;
    float h1 = e1 * rs2 * g2.y + b2.y;

    *(float2*)&hsh[w][2 * lane] = make_float2(h0, h1);
    __syncthreads();

    int j = lane & 7, i16 = lane >> 3;
    float xa = 0.f, ga = 0.f;
#pragma unroll
    for (int q = 0; q < 16; q++) {
        int qq = (q + 2 * i16) & 15;
        int i = i16 * 16 + qq;
        float hv = hsh[w][i];
        xa = fmaf(hv, w_low[i * BN_ + j], xa);
        ga = fmaf(hv, w_g1[i * BN_ + j], ga);
    }
#pragma unroll
    for (int m = 8; m <= 32; m <<= 1) {
        xa += __shfl_xor(xa, m, 64);
        ga += __shfl_xor(ga, m, 64);
    }
    xa += b_low[j];

    float mb = xa;
#pragma unroll
    for (int m = 1; m <= 4; m <<= 1) mb += __shfl_xor(mb, m, 64);
    mb *= (1.f / BN_);
    float db = xa - mb;
    float vb = db * db;
#pragma unroll
    for (int m = 1; m <= 4; m <<= 1) vb += __shfl_xor(vb, m, 64);
    vb *= (1.f / BN_);
    float rb = rsqrtf(vb + EPS_);
    float v = db * rb * ln_bn_g[j] + ln_bn_b[j];
    float xm = v / (1.f + __expf(-v));
    float u = ga + b_g1[j];
    float sg = u / (1.f + __expf(-u));
    if (lane < 8) { xms[w][lane] = xm; sgs[w][lane] = sg; }
    __syncthreads();

    if (lane < HOR_) {
        float ip = b_high[lane], gt = b_g2[lane];
#pragma unroll
        for (int jj = 0; jj < 8; jj++) {
            ip = fmaf(xms[w][jj], w_high[jj * HOR_ + lane], ip);
            gt = fmaf(sgs[w][jj], w_g2[jj * HOR_ + lane], gt);
        }
        float gate = 1.f / (1.f + __expf(-gt));
        float prog = last_step[g] * __expf(-0.1f * (float)(lane + 1));
        out[(size_t)g * HOR_ + lane] = gate * ip + (1.f - gate) * prog;
    }
}

extern "C" void kernel_launch(void* const* d_in, const int* in_sizes, int n_in,
                              void* d_out, int out_size, void* d_ws, size_t ws_size,
                              hipStream_t stream) {
    const float* x        = (const float*)d_in[0];
    const int*   adj      = (const int*)d_in[1];
    const float* last_step= (const float*)d_in[2];
    const float* loc_emb  = (const float*)d_in[3];
    const float* W_gat    = (const float*)d_in[4];
    const float* a_src    = (const float*)d_in[5];
    const float* a_dst    = (const float*)d_in[6];
    const float* ln_gat_g = (const float*)d_in[7];
    const float* ln_gat_b = (const float*)d_in[8];
    const float* ln_g     = (const float*)d_in[9];
    const float* ln_b     = (const float*)d_in[10];
    const float* w_low    = (const float*)d_in[11];
    const float* b_low    = (const float*)d_in[12];
    const float* ln_bn_g  = (const float*)d_in[13];
    const float* ln_bn_b  = (const float*)d_in[14];
    const float* w_high   = (const float*)d_in[15];
    const float* b_high   = (const float*)d_in[16];
    const float* w_g1     = (const float*)d_in[17];
    const float* b_g1     = (const float*)d_in[18];
    const float* w_g2     = (const float*)d_in[19];
    const float* b_g2     = (const float*)d_in[20];
    float* out = (float*)d_out;

    float* ws = (float*)d_ws;
    // Wh (f32) is consumed by k_ef before k_attn runs -> reuse its region for h_prime.
    float*        Wh      = ws;                                   // 2,048,000 f32
    float*        h_prime = ws;                                   // alias (after k_ef)
    __bf16*       Whbf    = (__bf16*)(ws + 2048000);              // 2,048,000 bf16
    __bf16*       WhT     = (__bf16*)(ws + 3072000);              // 32*32*2048 bf16
    float2*       Etab    = (float2*)(ws + 4120576);              // 64,000 float2
    float2*       Ftab    = (float2*)(ws + 4248576);              // 64,000 float2
    unsigned int* adjp    = (unsigned int*)(ws + 4376576);        // 128,000 u32
    __bf16*       Wpk     = (__bf16*)(ws + 4504576);              // 2 x 20,480 bf16

    hipLaunchKernelGGL(k_wprep, dim3(80),      dim3(256), 0, stream, W_gat, Wpk);
    hipLaunchKernelGGL(k_pack,  dim3(500),     dim3(256), 0, stream, adj, adjp);
    hipLaunchKernelGGL(k_wh,    dim3(500),     dim3(256), 0, stream, x, loc_emb, Wpk, Wh, Whbf);
    hipLaunchKernelGGL(k_ef,    dim3(250),     dim3(256), 0, stream, Wh, a_src, a_dst, Etab, Ftab);
    hipLaunchKernelGGL(k_tr,    dim3(16, 32),  dim3(256), 0, stream, Whbf, WhT);
    hipLaunchKernelGGL(k_attn,  dim3(32, 32),  dim3(256), 0, stream, WhT, Etab, Ftab, adjp, h_prime);
    hipLaunchKernelGGL(k_head,  dim3(4000),    dim3(256), 0, stream, h_prime, x, last_step,
                       ln_gat_g, ln_gat_b, ln_g, ln_b, w_low, b_low, ln_bn_g, ln_bn_b,
                       w_high, b_high, w_g1, b_g1, w_g2, b_g2, out);
}